// Round 17
// baseline (388.253 us; speedup 1.0000x reference)
//
#include <hip/hip_runtime.h>

#define NB 2048
#define TS 128
#define NS 16
#define MS 8
#define CS 4
#define DTC 0.01f

// ws layout (floats) — r13 layout
#define K_OFF 0
#define K_SZ (TS*NS*MS)           // 16,384
#define G_OFF (K_OFF + K_SZ)
#define G_SZ ((TS-1)*NS*NS)       // 32,512
#define PP_OFF (G_OFF + G_SZ)
#define PP_SZ (TS*NS*NS)          // 32,768
#define PF_OFF (PP_OFF + PP_SZ)
#define PF_SZ (TS*NS*NS)
#define A_OFF (PF_OFF + PF_SZ)
#define A_SZ (TS*NS*NS)           // A_t = (I-K H)F
#define M_OFF (A_OFF + A_SZ)
#define M_SZ (TS*NS*CS)           // M_t = DT(Bc - K HBc)

// explicit full-width shuffle within a 16-lane group (groups never span waves)
#define GSHFL(v, k) __shfl((v), ((tid & 48) | (k)), 64)

// single-wave fence: all prior LDS ops COMPLETE before anything after issues.
// (one wave => no s_barrier needed; "memory" clobber stops compiler reordering)
#define WFENCE() asm volatile("s_waitcnt lgkmcnt(0)" ::: "memory")

// ---------------------------------------------------------------------------
// Kernel A (round-17 rewrite): SINGLE-WAVE covariance recursion. 64 lanes,
// ZERO barriers. Lane L owns: row i=L>>2 cols 4q..4q+3 (q=L&3) of 16x16
// matrices; (a8=L>>3, c8=L&7) of 8x8; col-pair jw=2*(L&7) of 8x16.
// Math identical to r13/r14 (all previously-passing algebra):
//   TP = F*Pf ; W = HF*Pf ; Pp = TP*F^T+Q (stored) ; PHt = TP*HF^T+QHt ;
//   S = W*HF^T+Rbar ; HP = W*F^T+HQ ; per-lane LU of S, ONE solve (e_m),
//   two K-dots ; Pf = Pp-K*HP ; A = F-K*HF ; M = DT(Bc-K*HBc).
// No shuffles (r1/2/5 poison avoided); per-thread LU is r13-proven.
// ---------------------------------------------------------------------------
__global__ __launch_bounds__(64) void cov_wave(
    const float* __restrict__ Ag, const float* __restrict__ Hg,
    const float* __restrict__ Qg, const float* __restrict__ Rg,
    const float* __restrict__ P0g, const float* __restrict__ Bcg,
    float* __restrict__ Kw, float* __restrict__ Ppw, float* __restrict__ Pfw,
    float* __restrict__ Aw, float* __restrict__ Mw)
{
    __shared__ float Fs[NS][NS], Qs[NS][NS], Hs[MS][NS];
    __shared__ float HFs[MS][NS], QHt[NS][MS], Rs[MS][MS], Rbar[MS][MS];
    __shared__ float Bcs[NS][CS], HBcs[MS][CS];
    __shared__ float Pf[NS][NS], TP[NS][NS], Ws[MS][NS];
    __shared__ float PHt[NS][MS], HP[MS][NS], Sg[MS][MS], Ks[NS][MS];

    const int L  = threadIdx.x;
    const int i  = L >> 2, q = L & 3, jb = q * 4;   // 16x16 role
    const int a8 = L >> 3, c8 = L & 7;              // 8x8 role
    const int jw = (L & 7) * 2;                     // 8x16 col-pair role

    // ---- init loads ----
#pragma unroll
    for (int s = 0; s < 4; ++s) {
        const int tid = L + s*64, ii = tid >> 4, jj = tid & 15;
        Fs[ii][jj] = ((ii == jj) ? 1.f : 0.f) + DTC * Ag[tid];
        Qs[ii][jj] = Qg[tid];
        Pf[ii][jj] = P0g[tid];          // P0 identical for all batches
    }
#pragma unroll
    for (int s = 0; s < 2; ++s) {
        const int e = L + s*64;
        Hs[e >> 4][e & 15] = Hg[e];
    }
    Rs[a8][c8] = Rg[L];
    Bcs[i][q]  = Bcg[L];
    WFENCE();

    // HF = H*F, QHt = Q*H^T (2 els/lane each), HBc = H*Bc
#pragma unroll
    for (int s = 0; s < 2; ++s) {
        const int e = L + s*64;
        { const int a = e >> 4, k = e & 15;
          float acc = 0.f;
#pragma unroll
          for (int m = 0; m < NS; ++m) acc += Hs[a][m] * Fs[m][k];
          HFs[a][k] = acc; }
        { const int ii = e >> 3, b = e & 7;
          float acc = 0.f;
#pragma unroll
          for (int k = 0; k < NS; ++k) acc += Qs[ii][k] * Hs[b][k];
          QHt[ii][b] = acc; }
    }
    if (L < MS*CS) {
        const int r = L >> 2, c = L & 3;
        float acc = 0.f;
#pragma unroll
        for (int k = 0; k < NS; ++k) acc += Hs[r][k] * Bcs[k][c];
        HBcs[r][c] = acc;
    }
    WFENCE();

    {   // Rbar = H*QHt + R
        float acc = Rs[a8][c8];
#pragma unroll
        for (int k = 0; k < NS; ++k) acc += Hs[a8][k] * QHt[k][c8];
        Rbar[a8][c8] = acc;
    }
    WFENCE();

    // ---- persistent registers ----
    float Fri[NS], HFa[NS], F4[4][NS], HF2[2][NS];
#pragma unroll
    for (int k = 0; k < NS; ++k) Fri[k] = Fs[i][k];
#pragma unroll
    for (int k = 0; k < NS; ++k) HFa[k] = HFs[a8][k];
#pragma unroll
    for (int c = 0; c < 4; ++c)
#pragma unroll
        for (int k = 0; k < NS; ++k) F4[c][k] = Fs[jb + c][k];
#pragma unroll
    for (int d = 0; d < 2; ++d)
#pragma unroll
        for (int k = 0; k < NS; ++k) HF2[d][k] = HFs[2*q + d][k];
    WFENCE();

    for (int t = 0; t < TS; ++t) {
        // ---- A: TP[i][jb..jb+3] = F*Pf ; W[a8][jw..jw+1] = HF*Pf ----
        float t0 = 0.f, t1 = 0.f, t2 = 0.f, t3 = 0.f;
#pragma unroll
        for (int k = 0; k < NS; ++k) {
            const float4 pk = *(const float4*)&Pf[k][jb];
            t0 += Fri[k]*pk.x; t1 += Fri[k]*pk.y; t2 += Fri[k]*pk.z; t3 += Fri[k]*pk.w;
        }
        float w0 = 0.f, w1 = 0.f;
#pragma unroll
        for (int k = 0; k < NS; ++k) {
            const float2 p2 = *(const float2*)&Pf[k][jw];
            w0 += HFa[k]*p2.x; w1 += HFa[k]*p2.y;
        }
        *(float4*)&TP[i][jb] = make_float4(t0, t1, t2, t3);
        *(float2*)&Ws[a8][jw] = make_float2(w0, w1);
        WFENCE();

        // ---- B: pp (regs) ; PHt ; S ; HP ----
        float tpr[NS];
#pragma unroll
        for (int k4 = 0; k4 < 4; ++k4) {
            const float4 v = *(const float4*)&TP[i][k4*4];
            tpr[k4*4] = v.x; tpr[k4*4+1] = v.y; tpr[k4*4+2] = v.z; tpr[k4*4+3] = v.w;
        }
        float pp[4];
        {
            const float4 qv = *(const float4*)&Qs[i][jb];
            pp[0] = qv.x; pp[1] = qv.y; pp[2] = qv.z; pp[3] = qv.w;
#pragma unroll
            for (int c = 0; c < 4; ++c) {
                float acc = pp[c];
#pragma unroll
                for (int k = 0; k < NS; ++k) acc += tpr[k]*F4[c][k];
                pp[c] = acc;
            }
        }
        float ph0, ph1;
        {
            const float2 qh = *(const float2*)&QHt[i][2*q];
            ph0 = qh.x; ph1 = qh.y;
#pragma unroll
            for (int k = 0; k < NS; ++k) { ph0 += tpr[k]*HF2[0][k]; ph1 += tpr[k]*HF2[1][k]; }
        }
        float wr[NS];
#pragma unroll
        for (int k4 = 0; k4 < 4; ++k4) {
            const float4 v = *(const float4*)&Ws[a8][k4*4];
            wr[k4*4] = v.x; wr[k4*4+1] = v.y; wr[k4*4+2] = v.z; wr[k4*4+3] = v.w;
        }
        float sv = Rbar[a8][c8];
#pragma unroll
        for (int k4 = 0; k4 < 4; ++k4) {
            const float4 h = *(const float4*)&HFs[c8][k4*4];
            sv += wr[k4*4]*h.x + wr[k4*4+1]*h.y + wr[k4*4+2]*h.z + wr[k4*4+3]*h.w;
        }
        float hp0 = QHt[jw][a8], hp1 = QHt[jw+1][a8];   // HQ[m][jj] = QHt[jj][m] (Q sym)
#pragma unroll
        for (int k4 = 0; k4 < 4; ++k4) {
            const float4 f0 = *(const float4*)&Fs[jw][k4*4];
            const float4 f1 = *(const float4*)&Fs[jw+1][k4*4];
            hp0 += wr[k4*4]*f0.x + wr[k4*4+1]*f0.y + wr[k4*4+2]*f0.z + wr[k4*4+3]*f0.w;
            hp1 += wr[k4*4]*f1.x + wr[k4*4+1]*f1.y + wr[k4*4+2]*f1.z + wr[k4*4+3]*f1.w;
        }
        *(float2*)&PHt[i][2*q] = make_float2(ph0, ph1);
        Sg[a8][c8] = sv;
        *(float2*)&HP[a8][jw] = make_float2(hp0, hp1);
        WFENCE();

        // ---- C: per-lane LU of S (r13-proven), ONE solve e_m, two K-dots ----
        {
            float Sr[MS][MS];
#pragma unroll
            for (int rr = 0; rr < MS; ++rr) {
                const float4 x0 = *(const float4*)&Sg[rr][0];
                const float4 x1 = *(const float4*)&Sg[rr][4];
                Sr[rr][0]=x0.x; Sr[rr][1]=x0.y; Sr[rr][2]=x0.z; Sr[rr][3]=x0.w;
                Sr[rr][4]=x1.x; Sr[rr][5]=x1.y; Sr[rr][6]=x1.z; Sr[rr][7]=x1.w;
            }
            float rds[MS];
#pragma unroll
            for (int p = 0; p < MS; ++p) {
                const float rd = 1.f / Sr[p][p]; rds[p] = rd;
#pragma unroll
                for (int r = p+1; r < MS; ++r) {
                    const float f = Sr[r][p] * rd; Sr[r][p] = f;
#pragma unroll
                    for (int c = p+1; c < MS; ++c) Sr[r][c] -= f * Sr[p][c];
                }
            }
            const int m = c8;
            float yv[MS];
#pragma unroll
            for (int r = 0; r < MS; ++r) {
                float v = (r == m) ? 1.f : 0.f;
#pragma unroll
                for (int c = 0; c < r; ++c) v -= Sr[r][c] * yv[c];
                yv[r] = v;
            }
            float xv[MS];
#pragma unroll
            for (int r = MS-1; r >= 0; --r) {
                float v = yv[r];
#pragma unroll
                for (int c = r+1; c < MS; ++c) v -= Sr[r][c] * xv[c];
                xv[r] = v * rds[r];
            }
            const float4 pA0 = *(const float4*)&PHt[a8][0];
            const float4 pA1 = *(const float4*)&PHt[a8][4];
            const float4 pB0 = *(const float4*)&PHt[a8+8][0];
            const float4 pB1 = *(const float4*)&PHt[a8+8][4];
            const float kv0 = pA0.x*xv[0] + pA0.y*xv[1] + pA0.z*xv[2] + pA0.w*xv[3]
                            + pA1.x*xv[4] + pA1.y*xv[5] + pA1.z*xv[6] + pA1.w*xv[7];
            const float kv1 = pB0.x*xv[0] + pB0.y*xv[1] + pB0.z*xv[2] + pB0.w*xv[3]
                            + pB1.x*xv[4] + pB1.y*xv[5] + pB1.z*xv[6] + pB1.w*xv[7];
            Ks[a8][m]     = kv0;
            Ks[a8 + 8][m] = kv1;
            Kw[t*(NS*MS) + L]      = kv0;   // L == a8*8+m
            Kw[t*(NS*MS) + 64 + L] = kv1;   // L+64 == (a8+8)*8+m
        }
        WFENCE();

        // ---- D: Pf = Pp-K*HP ; A = F-K*HF ; M = DT(Bc-K*HBc) ; stores ----
        {
            float kr[MS];
            const float4 k0 = *(const float4*)&Ks[i][0];
            const float4 k1 = *(const float4*)&Ks[i][4];
            kr[0]=k0.x; kr[1]=k0.y; kr[2]=k0.z; kr[3]=k0.w;
            kr[4]=k1.x; kr[5]=k1.y; kr[6]=k1.z; kr[7]=k1.w;
            float pfv[4] = {pp[0], pp[1], pp[2], pp[3]};
            float av [4] = {Fri[jb], Fri[jb+1], Fri[jb+2], Fri[jb+3]};
#pragma unroll
            for (int m2 = 0; m2 < MS; ++m2) {
                const float4 hpv = *(const float4*)&HP[m2][jb];
                const float4 hfv = *(const float4*)&HFs[m2][jb];
                pfv[0] -= kr[m2]*hpv.x; pfv[1] -= kr[m2]*hpv.y;
                pfv[2] -= kr[m2]*hpv.z; pfv[3] -= kr[m2]*hpv.w;
                av[0]  -= kr[m2]*hfv.x; av[1]  -= kr[m2]*hfv.y;
                av[2]  -= kr[m2]*hfv.z; av[3]  -= kr[m2]*hfv.w;
            }
            *(float4*)&Pf[i][jb] = make_float4(pfv[0], pfv[1], pfv[2], pfv[3]);
            *(float4*)&Ppw[t*(NS*NS) + i*NS + jb] = make_float4(pp[0], pp[1], pp[2], pp[3]);
            *(float4*)&Pfw[t*(NS*NS) + i*NS + jb] = make_float4(pfv[0], pfv[1], pfv[2], pfv[3]);
            *(float4*)&Aw [t*(NS*NS) + i*NS + jb] = make_float4(av[0], av[1], av[2], av[3]);
            float mv = Bcs[i][q];
#pragma unroll
            for (int m2 = 0; m2 < MS; ++m2) mv -= kr[m2] * HBcs[m2][q];
            Mw[t*(NS*CS) + L] = DTC * mv;   // L == i*4+q
        }
        WFENCE();
    }
}

// ---------------------------------------------------------------------------
// Kernel B+P fused (round-13 exact): blockIdx < TS-1 -> smoother gain G_t;
// else -> prep: b_t = M_t*u_t + K_t*y_t into d_out.
// ---------------------------------------------------------------------------
__global__ __launch_bounds__(256) void gprep_kernel(
    const float* __restrict__ Ag,
    const float* __restrict__ Ppw, const float* __restrict__ Pfw,
    float* __restrict__ Gw,
    const float* __restrict__ ctrl, const float* __restrict__ obsg,
    const float* __restrict__ Kw, const float* __restrict__ Mw,
    float* __restrict__ outp)
{
    const int tid = threadIdx.x;
    __shared__ float aug0[NS][NS], aug1[NS][NS], Pfs[NS][NS], Wsh[NS][NS];

    if (blockIdx.x < TS-1) {
        const int t = blockIdx.x;
        const int r = tid >> 4, cl = tid & 15;

        float Frc[NS];
#pragma unroll
        for (int k = 0; k < NS; ++k) Frc[k] = ((cl == k) ? 1.f : 0.f) + DTC * Ag[cl*NS + k];

        aug0[r][cl] = Ppw[(t+1)*(NS*NS) + tid];
        aug1[r][cl] = (r == cl) ? 1.f : 0.f;
        Pfs[r][cl]  = Pfw[t*(NS*NS) + tid];
        __syncthreads();

        for (int p = 0; p < NS; ++p) {
            const float a0 = aug0[r][cl], a1 = aug1[r][cl];
            const float d  = aug0[p][p];
            const float pa = aug0[p][cl], pb = aug1[p][cl];
            const float f  = aug0[r][p];
            __syncthreads();
            const float rd = 1.f / d;
            if (r == p) { aug0[r][cl] = pa * rd;       aug1[r][cl] = pb * rd; }
            else        { const float frd = f * rd;
                          aug0[r][cl] = a0 - frd * pa; aug1[r][cl] = a1 - frd * pb; }
            __syncthreads();
        }

        float w0 = 0.f, w1 = 0.f;
#pragma unroll
        for (int k = 0; k < NS; k += 2) { w0 += Pfs[r][k]*Frc[k]; w1 += Pfs[r][k+1]*Frc[k+1]; }
        Wsh[r][cl] = w0 + w1;
        __syncthreads();

        float g0 = 0.f, g1 = 0.f;
#pragma unroll
        for (int k = 0; k < NS; k += 2) { g0 += Wsh[r][k]*aug1[k][cl]; g1 += Wsh[r][k+1]*aug1[k+1][cl]; }
        Gw[t*(NS*NS) + tid] = g0 + g1;
    } else {
        const int g = (blockIdx.x - (TS-1)) * 256 + tid;
        const int b = g >> 11;
        const int rem = g & 2047;
        const int t = rem >> 4, i = rem & 15;

        const float4 u  = *(const float4*)(ctrl + (size_t)b*TS*CS + t*CS);
        const float4 y0 = *(const float4*)(obsg + (size_t)b*TS*MS + t*MS);
        const float4 y1 = *(const float4*)(obsg + (size_t)b*TS*MS + t*MS + 4);
        const float4 mr = *(const float4*)(Mw + t*(NS*CS) + i*CS);
        const float4 k0 = *(const float4*)(Kw + t*(NS*MS) + i*MS);
        const float4 k1 = *(const float4*)(Kw + t*(NS*MS) + i*MS + 4);

        float v = mr.x*u.x + mr.y*u.y + mr.z*u.z + mr.w*u.w;
        v += k0.x*y0.x + k0.y*y0.y + k0.z*y0.z + k0.w*y0.w;
        v += k1.x*y1.x + k1.y*y1.y + k1.z*y1.z + k1.w*y1.w;
        outp[g] = v;
    }
}

// ---------------------------------------------------------------------------
// Kernel FB (round-13 exact): fused fwd+bwd, bulk b_t LDS load, 4-deep
// software pipelines with named buffers.
// ---------------------------------------------------------------------------
#define FWD_LOAD(B, T) do { \
    const float* ap_ = Aw + (T)*(NS*NS) + lane*NS; \
    B##a0 = *(const float4*)(ap_);      B##a1 = *(const float4*)(ap_ + 4); \
    B##a2 = *(const float4*)(ap_ + 8);  B##a3 = *(const float4*)(ap_ + 12); \
    B##bt = myslot[(T)*128]; \
} while (0)

#define FWD_STEP(T, B, TL) do { \
    float p0_ = B##bt, p1_ = 0.f, p2_ = 0.f, p3_ = 0.f; \
    p0_ += B##a0.x*GSHFL(s,0)  + B##a0.y*GSHFL(s,1); \
    p1_ += B##a0.z*GSHFL(s,2)  + B##a0.w*GSHFL(s,3); \
    p2_ += B##a1.x*GSHFL(s,4)  + B##a1.y*GSHFL(s,5); \
    p3_ += B##a1.z*GSHFL(s,6)  + B##a1.w*GSHFL(s,7); \
    p0_ += B##a2.x*GSHFL(s,8)  + B##a2.y*GSHFL(s,9); \
    p1_ += B##a2.z*GSHFL(s,10) + B##a2.w*GSHFL(s,11); \
    p2_ += B##a3.x*GSHFL(s,12) + B##a3.y*GSHFL(s,13); \
    p3_ += B##a3.z*GSHFL(s,14) + B##a3.w*GSHFL(s,15); \
    const float sn_ = (p0_ + p1_) + (p2_ + p3_); \
    myslot[(T)*128] = sn_; \
    s = sn_; \
    if ((TL) < TS) FWD_LOAD(B, TL); \
} while (0)

#define BWD_LOAD(B, T) do { \
    const float* gp_ = Gw + (T)*(NS*NS) + lane*NS; \
    B##g0 = *(const float4*)(gp_);      B##g1 = *(const float4*)(gp_ + 4); \
    B##g2 = *(const float4*)(gp_ + 8);  B##g3 = *(const float4*)(gp_ + 12); \
    B##u  = *(const float4*)(up + ((T)+1)*CS); \
    B##sf = myslot[(T)*128]; \
} while (0)

#define BWD_STEP(T, B, TL) do { \
    float p0_ = Bci[0]*B##u.x + Bci[1]*B##u.y; \
    float p1_ = Bci[2]*B##u.z + Bci[3]*B##u.w; \
    float p2_ = 0.f, p3_ = 0.f; \
    _Pragma("unroll") \
    for (int k = 0; k < NS; k += 4) { \
        p0_ += Fi[k  ] * GSHFL(B##sf, k); \
        p1_ += Fi[k+1] * GSHFL(B##sf, k+1); \
        p2_ += Fi[k+2] * GSHFL(B##sf, k+2); \
        p3_ += Fi[k+3] * GSHFL(B##sf, k+3); \
    } \
    const float diff_ = ss - ((p0_ + p1_) + (p2_ + p3_)); \
    float a0_ = B##g0.x*GSHFL(diff_,0)  + B##g0.y*GSHFL(diff_,1); \
    a0_      += B##g0.z*GSHFL(diff_,2)  + B##g0.w*GSHFL(diff_,3); \
    float a1_ = B##g1.x*GSHFL(diff_,4)  + B##g1.y*GSHFL(diff_,5); \
    a1_      += B##g1.z*GSHFL(diff_,6)  + B##g1.w*GSHFL(diff_,7); \
    float a2_ = B##g2.x*GSHFL(diff_,8)  + B##g2.y*GSHFL(diff_,9); \
    a2_      += B##g2.z*GSHFL(diff_,10) + B##g2.w*GSHFL(diff_,11); \
    float a3_ = B##g3.x*GSHFL(diff_,12) + B##g3.y*GSHFL(diff_,13); \
    a3_      += B##g3.z*GSHFL(diff_,14) + B##g3.w*GSHFL(diff_,15); \
    const float sn_ = B##sf + ((a0_ + a1_) + (a2_ + a3_)); \
    ob[(T)*NS + lane] = sn_; \
    ss = sn_; \
    if ((TL) >= 0) BWD_LOAD(B, TL); \
} while (0)

__global__ __launch_bounds__(128, 1) void fb_kernel(
    const float* __restrict__ s0g, const float* __restrict__ Aw,
    const float* __restrict__ Gw, const float* __restrict__ ctrl,
    const float* __restrict__ Ag, const float* __restrict__ Bcg,
    float* __restrict__ outp)
{
    extern __shared__ float sfs[];     // [TS][8][NS] = 64KB
    const int tid  = threadIdx.x;
    const int lane = tid & 15;
    const int wb   = tid >> 4;
    const int b    = blockIdx.x * 8 + wb;
    float* ob = outp + (size_t)b * TS * NS;
    float* myslot = sfs + wb*NS + lane;

    // ---- bulk-load b_t (written by prep) into LDS, fully coalesced ----
    {
        const float4* src = (const float4*)(outp + (size_t)(blockIdx.x*8) * TS * NS);
        float4* dst = (float4*)sfs;
        for (int idx = tid; idx < 4096; idx += 128) {
            const int wb2 = idx >> 9;
            const int k   = idx & 511;
            const float4 v = src[idx];
            dst[(k >> 2)*32 + wb2*4 + (k & 3)] = v;
        }
    }
    __syncthreads();

    // ---------------- phase 1: forward filter (4-deep pipeline) ----------------
    {
        float s = s0g[b*NS + lane];
        float4 Aa0, Aa1, Aa2, Aa3; float Abt;
        float4 Ba0, Ba1, Ba2, Ba3; float Bbt;
        float4 Ca0, Ca1, Ca2, Ca3; float Cbt;
        float4 Da0, Da1, Da2, Da3; float Dbt;
        FWD_LOAD(A, 0); FWD_LOAD(B, 1); FWD_LOAD(C, 2); FWD_LOAD(D, 3);

        for (int tb = 0; tb <= TS-4; tb += 4) {
            FWD_STEP(tb,   A, tb+4);
            FWD_STEP(tb+1, B, tb+5);
            FWD_STEP(tb+2, C, tb+6);
            FWD_STEP(tb+3, D, tb+7);
        }
    }

    // ---------------- phase 2: backward smoother (4-deep pipeline) ----------------
    {
        float Fi[NS], Bci[CS];
#pragma unroll
        for (int k = 0; k < NS; ++k) Fi[k] = ((lane == k) ? 1.f : 0.f) + DTC * Ag[lane*NS + k];
#pragma unroll
        for (int k = 0; k < CS; ++k) Bci[k] = DTC * Bcg[lane*CS + k];
        const float* up = ctrl + (size_t)b * TS * CS;

        float ss = myslot[(TS-1)*128];
        ob[(TS-1)*NS + lane] = ss;             // s_s[T-1] = s_f[T-1]

        float4 Ag0, Ag1, Ag2, Ag3, Au; float Asf;
        float4 Bg0, Bg1, Bg2, Bg3, Bu; float Bsf;
        float4 Cg0, Cg1, Cg2, Cg3, Cu; float Csf;
        float4 Dg0, Dg1, Dg2, Dg3, Du; float Dsf;
        BWD_LOAD(A, TS-2); BWD_LOAD(B, TS-3); BWD_LOAD(C, TS-4); BWD_LOAD(D, TS-5);

        for (int tb = TS-2; tb >= 6; tb -= 4) {
            BWD_STEP(tb,   A, tb-4);
            BWD_STEP(tb-1, B, tb-5);
            BWD_STEP(tb-2, C, tb-6);
            BWD_STEP(tb-3, D, tb-7);
        }
        BWD_STEP(2, A, -1);
        BWD_STEP(1, B, -1);
        BWD_STEP(0, C, -1);
    }
}

extern "C" void kernel_launch(void* const* d_in, const int* in_sizes, int n_in,
                              void* d_out, int out_size, void* d_ws, size_t ws_size,
                              hipStream_t stream)
{
    (void)out_size; (void)ws_size;

    // Self-resolving input mapping from element counts (the round-4 fix):
    const float *s0 = nullptr, *P0 = nullptr, *ctrl = nullptr, *obs = nullptr;
    const float *A = nullptr, *Bc = nullptr, *H = nullptr, *Q = nullptr, *R = nullptr;
    for (int idx = 0; idx < n_in; ++idx) {
        const float* p = (const float*)d_in[idx];
        switch (in_sizes[idx]) {
            case NB*NS:        s0   = p; break;           // 32768
            case NB*NS*NS:     P0   = p; break;           // 524288
            case NB*TS*CS:     ctrl = p; break;           // 1048576
            case NB*TS*MS:     obs  = p; break;           // 2097152
            case MS*NS:        H    = p; break;           // 128
            case NS*NS:        if (!A)  A  = p; else Q = p; break;   // 256
            case MS*MS:        if (!Bc) Bc = p; else R = p; break;   // 64
            default: break;
        }
    }

    float* ws  = (float*)d_ws;
    float* Kw  = ws + K_OFF;
    float* Gw  = ws + G_OFF;
    float* Ppw = ws + PP_OFF;
    float* Pfw = ws + PF_OFF;
    float* Aw  = ws + A_OFF;
    float* Mw  = ws + M_OFF;
    float* out = (float*)d_out;

    hipLaunchKernelGGL(cov_wave, dim3(1), dim3(64), 0, stream,
                       A, H, Q, R, P0, Bc, Kw, Ppw, Pfw, Aw, Mw);
    hipLaunchKernelGGL(gprep_kernel, dim3((TS-1) + NB*TS*NS/256), dim3(256), 0, stream,
                       A, Ppw, Pfw, Gw, ctrl, obs, Kw, Mw, out);
    hipLaunchKernelGGL(fb_kernel, dim3(NB/8), dim3(128), TS*8*NS*sizeof(float), stream,
                       s0, Aw, Gw, ctrl, A, Bc, out);
}

// Round 18
// 322.495 us; speedup vs baseline: 1.2039x; 1.2039x over previous
//
#include <hip/hip_runtime.h>

#define NB 2048
#define TS 128
#define NS 16
#define MS 8
#define CS 4
#define DTC 0.01f

// ws layout (floats)
#define K_OFF 0
#define K_SZ (TS*NS*MS)           // 16,384
#define G_OFF (K_OFF + K_SZ)
#define G_SZ ((TS-1)*NS*NS)       // 32,512
#define PP_OFF (G_OFF + G_SZ)
#define PP_SZ (TS*NS*NS)          // 32,768
#define PF_OFF (PP_OFF + PP_SZ)
#define PF_SZ (TS*NS*NS)
#define A_OFF (PF_OFF + PF_SZ)
#define A_SZ (TS*NS*NS)           // A_t = (I-K H)F
#define M_OFF (A_OFF + A_SZ)
#define M_SZ (TS*NS*CS)           // M_t = DT(Bc - K HBc)

// explicit full-width shuffle within a 16-lane group (groups never span waves)
#define GSHFL(v, k) __shfl((v), ((tid & 48) | (k)), 64)

// LDS-only barrier (passed R10+; drains lgkm only, global stores drift)
#define LBAR() do { \
    asm volatile("s_waitcnt lgkmcnt(0)" ::: "memory"); \
    __builtin_amdgcn_s_barrier(); \
    asm volatile("" ::: "memory"); \
} while (0)

// ---------------------------------------------------------------------------
// Kernel A: batch-independent covariance recursion — ROUND-13 EXACT
// (best measured 213 us; 4 stages/step, 4 waves, LDS-only barriers).
// cov structure verdict (r10..r17): fewer stages, more stages, 1 wave,
// 64 blocks, vote-exit all neutral-or-worse. Do not touch.
// ---------------------------------------------------------------------------
__global__ __launch_bounds__(256) void cov_kernel(
    const float* __restrict__ Ag, const float* __restrict__ Hg,
    const float* __restrict__ Qg, const float* __restrict__ Rg,
    const float* __restrict__ P0g, const float* __restrict__ Bcg,
    float* __restrict__ Kw, float* __restrict__ Ppw, float* __restrict__ Pfw,
    float* __restrict__ Aw, float* __restrict__ Mw)
{
    __shared__ float Fs[NS][NS], Qs[NS][NS];
    __shared__ float Hs[MS][NS], HFs[MS][NS], QHt[NS][MS];
    __shared__ float Rs[MS][MS], Rbar[MS][MS], HBcs[MS][CS], Bcs[NS][CS];
    __shared__ float Pf[NS][NS], Pp[NS][NS], TP[NS][NS], Ws[MS][NS];
    __shared__ float PHt[NS][MS], HP[MS][NS], Ks[NS][MS];
    __shared__ float Sg[MS][MS];

    const int tid = threadIdx.x;
    const int i = tid >> 4, j = tid & 15;

    float Fri[NS];
#pragma unroll
    for (int k = 0; k < NS; ++k) Fri[k] = ((i == k) ? 1.f : 0.f) + DTC * Ag[i*NS + k];

    Fs[i][j] = ((i == j) ? 1.f : 0.f) + DTC * Ag[tid];
    Qs[i][j] = Qg[tid];
    if (tid < MS*NS) Hs[tid >> 4][tid & 15] = Hg[tid];
    if (tid < MS*MS) Rs[tid >> 3][tid & 7] = Rg[tid];
    if (tid < NS*CS) Bcs[tid >> 2][tid & 3] = Bcg[tid];
    Pf[i][j] = P0g[tid];                 // P0 identical for all batches
    LBAR();

    if (tid < MS*NS) {
        const int a = tid >> 4, k = tid & 15;
        float acc = 0.f;
#pragma unroll
        for (int m = 0; m < NS; ++m) acc += Hs[a][m] * Fs[m][k];
        HFs[a][k] = acc;
    } else {
        const int e = tid - 128, ii = e >> 3, b = e & 7;
        float acc = 0.f;
#pragma unroll
        for (int k = 0; k < NS; ++k) acc += Qs[ii][k] * Hs[b][k];
        QHt[ii][b] = acc;
    }
    if (tid < MS*CS) {
        const int r = tid >> 2, c = tid & 3;
        float acc = 0.f;
#pragma unroll
        for (int k = 0; k < NS; ++k) acc += Hs[r][k] * Bcs[k][c];
        HBcs[r][c] = acc;
    }
    LBAR();

    if (tid < MS*MS) {
        const int r = tid >> 3, c = tid & 7;
        float acc = Rs[r][c];
#pragma unroll
        for (int k = 0; k < NS; ++k) acc += Hs[r][k] * QHt[k][c];
        Rbar[r][c] = acc;
    }
    LBAR();

    for (int t = 0; t < TS; ++t) {
        // ---- S1: TP = F*Pf (all 256)  ||  W = HF*Pf (tid<128) ----
        {
            float a0 = 0.f, a1 = 0.f;
#pragma unroll
            for (int k = 0; k < NS; k += 2) { a0 += Fri[k]*Pf[k][j]; a1 += Fri[k+1]*Pf[k+1][j]; }
            TP[i][j] = a0 + a1;
            if (tid < MS*NS) {
                const int a = tid >> 4, jj = tid & 15;
                float w0 = 0.f, w1 = 0.f;
#pragma unroll
                for (int k = 0; k < NS; k += 2) { w0 += HFs[a][k]*Pf[k][jj]; w1 += HFs[a][k+1]*Pf[k+1][jj]; }
                Ws[a][jj] = w0 + w1;
            }
        }
        LBAR();

        // ---- S2: Pp (all, own entry) || PHt (tid<128) || S (tid 128..191) ----
        {
            float c0 = Qs[i][j], c1 = 0.f;
#pragma unroll
            for (int k = 0; k < NS; k += 2) { c0 += TP[i][k]*Fs[j][k]; c1 += TP[i][k+1]*Fs[j][k+1]; }
            const float ppv = c0 + c1;
            Pp[i][j] = ppv;
            Ppw[t*(NS*NS) + tid] = ppv;
            if (tid < NS*MS) {
                const int ii = tid >> 3, l = tid & 7;
                float b0 = QHt[ii][l], b1 = 0.f;
#pragma unroll
                for (int k = 0; k < NS; k += 2) { b0 += TP[ii][k]*HFs[l][k]; b1 += TP[ii][k+1]*HFs[l][k+1]; }
                PHt[ii][l] = b0 + b1;
            } else if (tid < 192) {
                const int e = tid - 128, r = e >> 3, c = e & 7;
                float s0 = Rbar[r][c], s1 = 0.f;
#pragma unroll
                for (int k = 0; k < NS; k += 2) { s0 += Ws[r][k]*HFs[c][k]; s1 += Ws[r][k+1]*HFs[c][k+1]; }
                Sg[r][c] = s0 + s1;
            }
        }
        LBAR();

        // ---- S3: K-solve (tid<128, register LU)  ||  HP = H*Pp (tid>=128) ----
        if (tid < 128) {
            const int ii = tid >> 3, m = tid & 7;
            float Sr[MS][MS];
#pragma unroll
            for (int a = 0; a < MS; ++a) {
                const float4 x0 = *(const float4*)&Sg[a][0];
                const float4 x1 = *(const float4*)&Sg[a][4];
                Sr[a][0]=x0.x; Sr[a][1]=x0.y; Sr[a][2]=x0.z; Sr[a][3]=x0.w;
                Sr[a][4]=x1.x; Sr[a][5]=x1.y; Sr[a][6]=x1.z; Sr[a][7]=x1.w;
            }
            float rds[MS];
#pragma unroll
            for (int p = 0; p < MS; ++p) {
                const float rd = 1.f / Sr[p][p]; rds[p] = rd;
#pragma unroll
                for (int r = p+1; r < MS; ++r) {
                    const float f = Sr[r][p] * rd; Sr[r][p] = f;
#pragma unroll
                    for (int c = p+1; c < MS; ++c) Sr[r][c] -= f * Sr[p][c];
                }
            }
            float yv[MS];
#pragma unroll
            for (int r = 0; r < MS; ++r) {
                float v = (r == m) ? 1.f : 0.f;
#pragma unroll
                for (int c = 0; c < r; ++c) v -= Sr[r][c] * yv[c];
                yv[r] = v;
            }
            float xv[MS];
#pragma unroll
            for (int r = MS-1; r >= 0; --r) {
                float v = yv[r];
#pragma unroll
                for (int c = r+1; c < MS; ++c) v -= Sr[r][c] * xv[c];
                xv[r] = v * rds[r];
            }
            const float4 p0 = *(const float4*)&PHt[ii][0];
            const float4 p1 = *(const float4*)&PHt[ii][4];
            float kv = p0.x*xv[0] + p0.y*xv[1] + p0.z*xv[2] + p0.w*xv[3]
                     + p1.x*xv[4] + p1.y*xv[5] + p1.z*xv[6] + p1.w*xv[7];
            Ks[ii][m] = kv;
            Kw[t*(NS*MS) + tid] = kv;
        } else {
            const int e = tid - 128, m = e >> 4, jj = e & 15;
            float v = 0.f;
#pragma unroll
            for (int k = 0; k < NS; ++k) v += Hs[m][k] * Pp[k][jj];
            HP[m][jj] = v;
        }
        LBAR();

        // ---- S4: Pf = Pp - K*HP ; A_t = F - K*HF ; M_t = DT(Bc - K*HBc) ----
        {
            float kr[MS];
            *(float4*)&kr[0] = *(const float4*)&Ks[i][0];
            *(float4*)&kr[4] = *(const float4*)&Ks[i][4];
            float pf = Pp[i][j], av = Fs[i][j];
#pragma unroll
            for (int m = 0; m < MS; ++m) { pf -= kr[m] * HP[m][j]; av -= kr[m] * HFs[m][j]; }
            Pf[i][j] = pf;
            Pfw[t*(NS*NS) + tid] = pf;
            Aw[t*(NS*NS) + tid] = av;
            if (tid < NS*CS) {
                const int ri = tid >> 2, c = tid & 3;
                float mv = Bcs[ri][c];
#pragma unroll
                for (int m = 0; m < MS; ++m) mv -= Ks[ri][m] * HBcs[m][c];
                Mw[t*(NS*CS) + tid] = DTC * mv;
            }
        }
        LBAR();
    }
}

// ---------------------------------------------------------------------------
// Kernel B: smoother gains only (prep removed — b_t now computed inside fb).
// r13's g-part verbatim; grid = TS-1 blocks.
// ---------------------------------------------------------------------------
__global__ __launch_bounds__(256) void g_kernel(
    const float* __restrict__ Ag,
    const float* __restrict__ Ppw, const float* __restrict__ Pfw,
    float* __restrict__ Gw)
{
    const int t   = blockIdx.x;
    const int tid = threadIdx.x;
    const int r = tid >> 4, cl = tid & 15;

    __shared__ float aug0[NS][NS], aug1[NS][NS], Pfs[NS][NS], Wsh[NS][NS];

    float Frc[NS];
#pragma unroll
    for (int k = 0; k < NS; ++k) Frc[k] = ((cl == k) ? 1.f : 0.f) + DTC * Ag[cl*NS + k];

    aug0[r][cl] = Ppw[(t+1)*(NS*NS) + tid];
    aug1[r][cl] = (r == cl) ? 1.f : 0.f;
    Pfs[r][cl]  = Pfw[t*(NS*NS) + tid];
    __syncthreads();

    for (int p = 0; p < NS; ++p) {
        const float a0 = aug0[r][cl], a1 = aug1[r][cl];
        const float d  = aug0[p][p];
        const float pa = aug0[p][cl], pb = aug1[p][cl];
        const float f  = aug0[r][p];
        __syncthreads();
        const float rd = 1.f / d;
        if (r == p) { aug0[r][cl] = pa * rd;       aug1[r][cl] = pb * rd; }
        else        { const float frd = f * rd;
                      aug0[r][cl] = a0 - frd * pa; aug1[r][cl] = a1 - frd * pb; }
        __syncthreads();
    }

    float w0 = 0.f, w1 = 0.f;
#pragma unroll
    for (int k = 0; k < NS; k += 2) { w0 += Pfs[r][k]*Frc[k]; w1 += Pfs[r][k+1]*Frc[k+1]; }
    Wsh[r][cl] = w0 + w1;
    __syncthreads();

    float g0 = 0.f, g1 = 0.f;
#pragma unroll
    for (int k = 0; k < NS; k += 2) { g0 += Wsh[r][k]*aug1[k][cl]; g1 += Wsh[r][k+1]*aug1[k+1][cl]; }
    Gw[t*(NS*NS) + tid] = g0 + g1;
}

// ---------------------------------------------------------------------------
// Kernel FB (r13 + inline-b): bulk phase COMPUTES b_t = M_t*u_t + K_t*y_t
// directly into LDS (batch-parallel, prep's FMA order byte-identical) —
// removes prep's 16MB d_out write + fb's 16MB read. Phases 1/2 = r13 exact.
// ---------------------------------------------------------------------------
#define FWD_LOAD(B, T) do { \
    const float* ap_ = Aw + (T)*(NS*NS) + lane*NS; \
    B##a0 = *(const float4*)(ap_);      B##a1 = *(const float4*)(ap_ + 4); \
    B##a2 = *(const float4*)(ap_ + 8);  B##a3 = *(const float4*)(ap_ + 12); \
    B##bt = myslot[(T)*128]; \
} while (0)

#define FWD_STEP(T, B, TL) do { \
    float p0_ = B##bt, p1_ = 0.f, p2_ = 0.f, p3_ = 0.f; \
    p0_ += B##a0.x*GSHFL(s,0)  + B##a0.y*GSHFL(s,1); \
    p1_ += B##a0.z*GSHFL(s,2)  + B##a0.w*GSHFL(s,3); \
    p2_ += B##a1.x*GSHFL(s,4)  + B##a1.y*GSHFL(s,5); \
    p3_ += B##a1.z*GSHFL(s,6)  + B##a1.w*GSHFL(s,7); \
    p0_ += B##a2.x*GSHFL(s,8)  + B##a2.y*GSHFL(s,9); \
    p1_ += B##a2.z*GSHFL(s,10) + B##a2.w*GSHFL(s,11); \
    p2_ += B##a3.x*GSHFL(s,12) + B##a3.y*GSHFL(s,13); \
    p3_ += B##a3.z*GSHFL(s,14) + B##a3.w*GSHFL(s,15); \
    const float sn_ = (p0_ + p1_) + (p2_ + p3_); \
    myslot[(T)*128] = sn_; \
    s = sn_; \
    if ((TL) < TS) FWD_LOAD(B, TL); \
} while (0)

#define BWD_LOAD(B, T) do { \
    const float* gp_ = Gw + (T)*(NS*NS) + lane*NS; \
    B##g0 = *(const float4*)(gp_);      B##g1 = *(const float4*)(gp_ + 4); \
    B##g2 = *(const float4*)(gp_ + 8);  B##g3 = *(const float4*)(gp_ + 12); \
    B##u  = *(const float4*)(up + ((T)+1)*CS); \
    B##sf = myslot[(T)*128]; \
} while (0)

#define BWD_STEP(T, B, TL) do { \
    float p0_ = Bci[0]*B##u.x + Bci[1]*B##u.y; \
    float p1_ = Bci[2]*B##u.z + Bci[3]*B##u.w; \
    float p2_ = 0.f, p3_ = 0.f; \
    _Pragma("unroll") \
    for (int k = 0; k < NS; k += 4) { \
        p0_ += Fi[k  ] * GSHFL(B##sf, k); \
        p1_ += Fi[k+1] * GSHFL(B##sf, k+1); \
        p2_ += Fi[k+2] * GSHFL(B##sf, k+2); \
        p3_ += Fi[k+3] * GSHFL(B##sf, k+3); \
    } \
    const float diff_ = ss - ((p0_ + p1_) + (p2_ + p3_)); \
    float a0_ = B##g0.x*GSHFL(diff_,0)  + B##g0.y*GSHFL(diff_,1); \
    a0_      += B##g0.z*GSHFL(diff_,2)  + B##g0.w*GSHFL(diff_,3); \
    float a1_ = B##g1.x*GSHFL(diff_,4)  + B##g1.y*GSHFL(diff_,5); \
    a1_      += B##g1.z*GSHFL(diff_,6)  + B##g1.w*GSHFL(diff_,7); \
    float a2_ = B##g2.x*GSHFL(diff_,8)  + B##g2.y*GSHFL(diff_,9); \
    a2_      += B##g2.z*GSHFL(diff_,10) + B##g2.w*GSHFL(diff_,11); \
    float a3_ = B##g3.x*GSHFL(diff_,12) + B##g3.y*GSHFL(diff_,13); \
    a3_      += B##g3.z*GSHFL(diff_,14) + B##g3.w*GSHFL(diff_,15); \
    const float sn_ = B##sf + ((a0_ + a1_) + (a2_ + a3_)); \
    ob[(T)*NS + lane] = sn_; \
    ss = sn_; \
    if ((TL) >= 0) BWD_LOAD(B, TL); \
} while (0)

__global__ __launch_bounds__(128, 1) void fb_kernel(
    const float* __restrict__ s0g, const float* __restrict__ Aw,
    const float* __restrict__ Gw, const float* __restrict__ ctrl,
    const float* __restrict__ obsg, const float* __restrict__ Kw,
    const float* __restrict__ Mw, const float* __restrict__ Ag,
    const float* __restrict__ Bcg, float* __restrict__ outp)
{
    extern __shared__ float sfs[];     // [TS][8][NS] = 64KB
    const int tid  = threadIdx.x;
    const int lane = tid & 15;
    const int wb   = tid >> 4;
    const int b    = blockIdx.x * 8 + wb;
    float* ob = outp + (size_t)b * TS * NS;
    float* myslot = sfs + wb*NS + lane;

    const float* up = ctrl + (size_t)b * TS * CS;
    const float* yp = obsg + (size_t)b * TS * MS;

    // ---- bulk-COMPUTE b_t = M_t*u_t + K_t*y_t into LDS (prep math order) ----
    for (int t = 0; t < TS; ++t) {
        const float4 u  = *(const float4*)(up + t*CS);
        const float4 y0 = *(const float4*)(yp + t*MS);
        const float4 y1 = *(const float4*)(yp + t*MS + 4);
        const float4 mr = *(const float4*)(Mw + t*(NS*CS) + lane*CS);
        const float4 k0 = *(const float4*)(Kw + t*(NS*MS) + lane*MS);
        const float4 k1 = *(const float4*)(Kw + t*(NS*MS) + lane*MS + 4);

        float v = mr.x*u.x + mr.y*u.y + mr.z*u.z + mr.w*u.w;
        v += k0.x*y0.x + k0.y*y0.y + k0.z*y0.z + k0.w*y0.w;
        v += k1.x*y1.x + k1.y*y1.y + k1.z*y1.z + k1.w*y1.w;
        myslot[t*128] = v;
    }
    __syncthreads();

    // ---------------- phase 1: forward filter (4-deep pipeline) ----------------
    {
        float s = s0g[b*NS + lane];
        float4 Aa0, Aa1, Aa2, Aa3; float Abt;
        float4 Ba0, Ba1, Ba2, Ba3; float Bbt;
        float4 Ca0, Ca1, Ca2, Ca3; float Cbt;
        float4 Da0, Da1, Da2, Da3; float Dbt;
        FWD_LOAD(A, 0); FWD_LOAD(B, 1); FWD_LOAD(C, 2); FWD_LOAD(D, 3);

        for (int tb = 0; tb <= TS-4; tb += 4) {
            FWD_STEP(tb,   A, tb+4);
            FWD_STEP(tb+1, B, tb+5);
            FWD_STEP(tb+2, C, tb+6);
            FWD_STEP(tb+3, D, tb+7);
        }
    }

    // ---------------- phase 2: backward smoother (4-deep pipeline) ----------------
    {
        float Fi[NS], Bci[CS];
#pragma unroll
        for (int k = 0; k < NS; ++k) Fi[k] = ((lane == k) ? 1.f : 0.f) + DTC * Ag[lane*NS + k];
#pragma unroll
        for (int k = 0; k < CS; ++k) Bci[k] = DTC * Bcg[lane*CS + k];

        float ss = myslot[(TS-1)*128];
        ob[(TS-1)*NS + lane] = ss;             // s_s[T-1] = s_f[T-1]

        float4 Ag0, Ag1, Ag2, Ag3, Au; float Asf;
        float4 Bg0, Bg1, Bg2, Bg3, Bu; float Bsf;
        float4 Cg0, Cg1, Cg2, Cg3, Cu; float Csf;
        float4 Dg0, Dg1, Dg2, Dg3, Du; float Dsf;
        BWD_LOAD(A, TS-2); BWD_LOAD(B, TS-3); BWD_LOAD(C, TS-4); BWD_LOAD(D, TS-5);

        for (int tb = TS-2; tb >= 6; tb -= 4) {
            BWD_STEP(tb,   A, tb-4);
            BWD_STEP(tb-1, B, tb-5);
            BWD_STEP(tb-2, C, tb-6);
            BWD_STEP(tb-3, D, tb-7);
        }
        BWD_STEP(2, A, -1);
        BWD_STEP(1, B, -1);
        BWD_STEP(0, C, -1);
    }
}

extern "C" void kernel_launch(void* const* d_in, const int* in_sizes, int n_in,
                              void* d_out, int out_size, void* d_ws, size_t ws_size,
                              hipStream_t stream)
{
    (void)out_size; (void)ws_size;

    // Self-resolving input mapping from element counts (the round-4 fix):
    const float *s0 = nullptr, *P0 = nullptr, *ctrl = nullptr, *obs = nullptr;
    const float *A = nullptr, *Bc = nullptr, *H = nullptr, *Q = nullptr, *R = nullptr;
    for (int idx = 0; idx < n_in; ++idx) {
        const float* p = (const float*)d_in[idx];
        switch (in_sizes[idx]) {
            case NB*NS:        s0   = p; break;           // 32768
            case NB*NS*NS:     P0   = p; break;           // 524288
            case NB*TS*CS:     ctrl = p; break;           // 1048576
            case NB*TS*MS:     obs  = p; break;           // 2097152
            case MS*NS:        H    = p; break;           // 128
            case NS*NS:        if (!A)  A  = p; else Q = p; break;   // 256
            case MS*MS:        if (!Bc) Bc = p; else R = p; break;   // 64
            default: break;
        }
    }

    float* ws  = (float*)d_ws;
    float* Kw  = ws + K_OFF;
    float* Gw  = ws + G_OFF;
    float* Ppw = ws + PP_OFF;
    float* Pfw = ws + PF_OFF;
    float* Aw  = ws + A_OFF;
    float* Mw  = ws + M_OFF;
    float* out = (float*)d_out;

    hipLaunchKernelGGL(cov_kernel, dim3(1), dim3(256), 0, stream,
                       A, H, Q, R, P0, Bc, Kw, Ppw, Pfw, Aw, Mw);
    hipLaunchKernelGGL(g_kernel, dim3(TS-1), dim3(256), 0, stream,
                       A, Ppw, Pfw, Gw);
    hipLaunchKernelGGL(fb_kernel, dim3(NB/8), dim3(128), TS*8*NS*sizeof(float), stream,
                       s0, Aw, Gw, ctrl, obs, Kw, Mw, A, Bc, out);
}

// Round 19
// 312.732 us; speedup vs baseline: 1.2415x; 1.0312x over previous
//
#include <hip/hip_runtime.h>

#define NB 2048
#define TS 128
#define NS 16
#define MS 8
#define CS 4
#define DTC 0.01f

// ws layout (floats) — ~620 KB total
#define K_OFF 0
#define K_SZ (TS*NS*MS)           // 16,384
#define G_OFF (K_OFF + K_SZ)
#define G_SZ ((TS-1)*NS*NS)       // 32,512
#define PP_OFF (G_OFF + G_SZ)
#define PP_SZ (TS*NS*NS)          // 32,768
#define PF_OFF (PP_OFF + PP_SZ)
#define PF_SZ (TS*NS*NS)
#define A_OFF (PF_OFF + PF_SZ)
#define A_SZ (TS*NS*NS)           // A_t = (I-K H)F
#define M_OFF (A_OFF + A_SZ)
#define M_SZ (TS*NS*CS)           // M_t = DT(Bc - K HBc)

// explicit full-width shuffle within a 16-lane group (groups never span waves)
#define GSHFL(v, k) __shfl((v), ((tid & 48) | (k)), 64)

// LDS-only barrier (drains lgkm only; global stores drift past the barrier)
#define LBAR() do { \
    asm volatile("s_waitcnt lgkmcnt(0)" ::: "memory"); \
    __builtin_amdgcn_s_barrier(); \
    asm volatile("" ::: "memory"); \
} while (0)

// ---------------------------------------------------------------------------
// Kernel A: batch-independent covariance recursion — champion structure
// (4 stages/step, 4 waves, LDS-only barriers). Measured 212-213 us.
// ---------------------------------------------------------------------------
__global__ __launch_bounds__(256) void cov_kernel(
    const float* __restrict__ Ag, const float* __restrict__ Hg,
    const float* __restrict__ Qg, const float* __restrict__ Rg,
    const float* __restrict__ P0g, const float* __restrict__ Bcg,
    float* __restrict__ Kw, float* __restrict__ Ppw, float* __restrict__ Pfw,
    float* __restrict__ Aw, float* __restrict__ Mw)
{
    __shared__ float Fs[NS][NS], Qs[NS][NS];
    __shared__ float Hs[MS][NS], HFs[MS][NS], QHt[NS][MS];
    __shared__ float Rs[MS][MS], Rbar[MS][MS], HBcs[MS][CS], Bcs[NS][CS];
    __shared__ float Pf[NS][NS], Pp[NS][NS], TP[NS][NS], Ws[MS][NS];
    __shared__ float PHt[NS][MS], HP[MS][NS], Ks[NS][MS];
    __shared__ float Sg[MS][MS];

    const int tid = threadIdx.x;
    const int i = tid >> 4, j = tid & 15;

    float Fri[NS];
#pragma unroll
    for (int k = 0; k < NS; ++k) Fri[k] = ((i == k) ? 1.f : 0.f) + DTC * Ag[i*NS + k];

    Fs[i][j] = ((i == j) ? 1.f : 0.f) + DTC * Ag[tid];
    Qs[i][j] = Qg[tid];
    if (tid < MS*NS) Hs[tid >> 4][tid & 15] = Hg[tid];
    if (tid < MS*MS) Rs[tid >> 3][tid & 7] = Rg[tid];
    if (tid < NS*CS) Bcs[tid >> 2][tid & 3] = Bcg[tid];
    Pf[i][j] = P0g[tid];                 // P0 identical for all batches
    LBAR();

    if (tid < MS*NS) {
        const int a = tid >> 4, k = tid & 15;
        float acc = 0.f;
#pragma unroll
        for (int m = 0; m < NS; ++m) acc += Hs[a][m] * Fs[m][k];
        HFs[a][k] = acc;
    } else {
        const int e = tid - 128, ii = e >> 3, b = e & 7;
        float acc = 0.f;
#pragma unroll
        for (int k = 0; k < NS; ++k) acc += Qs[ii][k] * Hs[b][k];
        QHt[ii][b] = acc;
    }
    if (tid < MS*CS) {
        const int r = tid >> 2, c = tid & 3;
        float acc = 0.f;
#pragma unroll
        for (int k = 0; k < NS; ++k) acc += Hs[r][k] * Bcs[k][c];
        HBcs[r][c] = acc;
    }
    LBAR();

    if (tid < MS*MS) {
        const int r = tid >> 3, c = tid & 7;
        float acc = Rs[r][c];
#pragma unroll
        for (int k = 0; k < NS; ++k) acc += Hs[r][k] * QHt[k][c];
        Rbar[r][c] = acc;
    }
    LBAR();

    for (int t = 0; t < TS; ++t) {
        // ---- S1: TP = F*Pf (all 256)  ||  W = HF*Pf (tid<128) ----
        {
            float a0 = 0.f, a1 = 0.f;
#pragma unroll
            for (int k = 0; k < NS; k += 2) { a0 += Fri[k]*Pf[k][j]; a1 += Fri[k+1]*Pf[k+1][j]; }
            TP[i][j] = a0 + a1;
            if (tid < MS*NS) {
                const int a = tid >> 4, jj = tid & 15;
                float w0 = 0.f, w1 = 0.f;
#pragma unroll
                for (int k = 0; k < NS; k += 2) { w0 += HFs[a][k]*Pf[k][jj]; w1 += HFs[a][k+1]*Pf[k+1][jj]; }
                Ws[a][jj] = w0 + w1;
            }
        }
        LBAR();

        // ---- S2: Pp (all, own entry) || PHt (tid<128) || S (tid 128..191) ----
        {
            float c0 = Qs[i][j], c1 = 0.f;
#pragma unroll
            for (int k = 0; k < NS; k += 2) { c0 += TP[i][k]*Fs[j][k]; c1 += TP[i][k+1]*Fs[j][k+1]; }
            const float ppv = c0 + c1;
            Pp[i][j] = ppv;
            Ppw[t*(NS*NS) + tid] = ppv;
            if (tid < NS*MS) {
                const int ii = tid >> 3, l = tid & 7;
                float b0 = QHt[ii][l], b1 = 0.f;
#pragma unroll
                for (int k = 0; k < NS; k += 2) { b0 += TP[ii][k]*HFs[l][k]; b1 += TP[ii][k+1]*HFs[l][k+1]; }
                PHt[ii][l] = b0 + b1;
            } else if (tid < 192) {
                const int e = tid - 128, r = e >> 3, c = e & 7;
                float s0 = Rbar[r][c], s1 = 0.f;
#pragma unroll
                for (int k = 0; k < NS; k += 2) { s0 += Ws[r][k]*HFs[c][k]; s1 += Ws[r][k+1]*HFs[c][k+1]; }
                Sg[r][c] = s0 + s1;
            }
        }
        LBAR();

        // ---- S3: K-solve (tid<128, register LU)  ||  HP = H*Pp (tid>=128) ----
        if (tid < 128) {
            const int ii = tid >> 3, m = tid & 7;
            float Sr[MS][MS];
#pragma unroll
            for (int a = 0; a < MS; ++a) {
                const float4 x0 = *(const float4*)&Sg[a][0];
                const float4 x1 = *(const float4*)&Sg[a][4];
                Sr[a][0]=x0.x; Sr[a][1]=x0.y; Sr[a][2]=x0.z; Sr[a][3]=x0.w;
                Sr[a][4]=x1.x; Sr[a][5]=x1.y; Sr[a][6]=x1.z; Sr[a][7]=x1.w;
            }
            float rds[MS];
#pragma unroll
            for (int p = 0; p < MS; ++p) {
                const float rd = 1.f / Sr[p][p]; rds[p] = rd;
#pragma unroll
                for (int r = p+1; r < MS; ++r) {
                    const float f = Sr[r][p] * rd; Sr[r][p] = f;
#pragma unroll
                    for (int c = p+1; c < MS; ++c) Sr[r][c] -= f * Sr[p][c];
                }
            }
            float yv[MS];
#pragma unroll
            for (int r = 0; r < MS; ++r) {
                float v = (r == m) ? 1.f : 0.f;
#pragma unroll
                for (int c = 0; c < r; ++c) v -= Sr[r][c] * yv[c];
                yv[r] = v;
            }
            float xv[MS];
#pragma unroll
            for (int r = MS-1; r >= 0; --r) {
                float v = yv[r];
#pragma unroll
                for (int c = r+1; c < MS; ++c) v -= Sr[r][c] * xv[c];
                xv[r] = v * rds[r];
            }
            const float4 p0 = *(const float4*)&PHt[ii][0];
            const float4 p1 = *(const float4*)&PHt[ii][4];
            float kv = p0.x*xv[0] + p0.y*xv[1] + p0.z*xv[2] + p0.w*xv[3]
                     + p1.x*xv[4] + p1.y*xv[5] + p1.z*xv[6] + p1.w*xv[7];
            Ks[ii][m] = kv;
            Kw[t*(NS*MS) + tid] = kv;
        } else {
            const int e = tid - 128, m = e >> 4, jj = e & 15;
            float v = 0.f;
#pragma unroll
            for (int k = 0; k < NS; ++k) v += Hs[m][k] * Pp[k][jj];
            HP[m][jj] = v;
        }
        LBAR();

        // ---- S4: Pf = Pp - K*HP ; A_t = F - K*HF ; M_t = DT(Bc - K*HBc) ----
        {
            float kr[MS];
            *(float4*)&kr[0] = *(const float4*)&Ks[i][0];
            *(float4*)&kr[4] = *(const float4*)&Ks[i][4];
            float pf = Pp[i][j], av = Fs[i][j];
#pragma unroll
            for (int m = 0; m < MS; ++m) { pf -= kr[m] * HP[m][j]; av -= kr[m] * HFs[m][j]; }
            Pf[i][j] = pf;
            Pfw[t*(NS*NS) + tid] = pf;
            Aw[t*(NS*NS) + tid] = av;
            if (tid < NS*CS) {
                const int ri = tid >> 2, c = tid & 3;
                float mv = Bcs[ri][c];
#pragma unroll
                for (int m = 0; m < MS; ++m) mv -= Ks[ri][m] * HBcs[m][c];
                Mw[t*(NS*CS) + tid] = DTC * mv;
            }
        }
        LBAR();
    }
}

// ---------------------------------------------------------------------------
// Kernel B+P fused: blockIdx < TS-1 -> smoother gain G_t;
// else -> prep: b_t = M_t*u_t + K_t*y_t into d_out (wide, 8192 waves).
// ---------------------------------------------------------------------------
__global__ __launch_bounds__(256) void gprep_kernel(
    const float* __restrict__ Ag,
    const float* __restrict__ Ppw, const float* __restrict__ Pfw,
    float* __restrict__ Gw,
    const float* __restrict__ ctrl, const float* __restrict__ obsg,
    const float* __restrict__ Kw, const float* __restrict__ Mw,
    float* __restrict__ outp)
{
    const int tid = threadIdx.x;
    __shared__ float aug0[NS][NS], aug1[NS][NS], Pfs[NS][NS], Wsh[NS][NS];

    if (blockIdx.x < TS-1) {
        const int t = blockIdx.x;
        const int r = tid >> 4, cl = tid & 15;

        float Frc[NS];
#pragma unroll
        for (int k = 0; k < NS; ++k) Frc[k] = ((cl == k) ? 1.f : 0.f) + DTC * Ag[cl*NS + k];

        aug0[r][cl] = Ppw[(t+1)*(NS*NS) + tid];
        aug1[r][cl] = (r == cl) ? 1.f : 0.f;
        Pfs[r][cl]  = Pfw[t*(NS*NS) + tid];
        __syncthreads();

        for (int p = 0; p < NS; ++p) {
            const float a0 = aug0[r][cl], a1 = aug1[r][cl];
            const float d  = aug0[p][p];
            const float pa = aug0[p][cl], pb = aug1[p][cl];
            const float f  = aug0[r][p];
            __syncthreads();
            const float rd = 1.f / d;
            if (r == p) { aug0[r][cl] = pa * rd;       aug1[r][cl] = pb * rd; }
            else        { const float frd = f * rd;
                          aug0[r][cl] = a0 - frd * pa; aug1[r][cl] = a1 - frd * pb; }
            __syncthreads();
        }

        float w0 = 0.f, w1 = 0.f;
#pragma unroll
        for (int k = 0; k < NS; k += 2) { w0 += Pfs[r][k]*Frc[k]; w1 += Pfs[r][k+1]*Frc[k+1]; }
        Wsh[r][cl] = w0 + w1;
        __syncthreads();

        float g0 = 0.f, g1 = 0.f;
#pragma unroll
        for (int k = 0; k < NS; k += 2) { g0 += Wsh[r][k]*aug1[k][cl]; g1 += Wsh[r][k+1]*aug1[k+1][cl]; }
        Gw[t*(NS*NS) + tid] = g0 + g1;
    } else {
        const int g = (blockIdx.x - (TS-1)) * 256 + tid;
        const int b = g >> 11;
        const int rem = g & 2047;
        const int t = rem >> 4, i = rem & 15;

        const float4 u  = *(const float4*)(ctrl + (size_t)b*TS*CS + t*CS);
        const float4 y0 = *(const float4*)(obsg + (size_t)b*TS*MS + t*MS);
        const float4 y1 = *(const float4*)(obsg + (size_t)b*TS*MS + t*MS + 4);
        const float4 mr = *(const float4*)(Mw + t*(NS*CS) + i*CS);
        const float4 k0 = *(const float4*)(Kw + t*(NS*MS) + i*MS);
        const float4 k1 = *(const float4*)(Kw + t*(NS*MS) + i*MS + 4);

        float v = mr.x*u.x + mr.y*u.y + mr.z*u.z + mr.w*u.w;
        v += k0.x*y0.x + k0.y*y0.y + k0.z*y0.z + k0.w*y0.w;
        v += k1.x*y1.x + k1.y*y1.y + k1.z*y1.z + k1.w*y1.w;
        outp[g] = v;
    }
}

// ---------------------------------------------------------------------------
// Kernel FB: fused fwd+bwd, bulk b_t LDS load, 4-deep software pipelines
// with named buffers (champion configuration).
// ---------------------------------------------------------------------------
#define FWD_LOAD(B, T) do { \
    const float* ap_ = Aw + (T)*(NS*NS) + lane*NS; \
    B##a0 = *(const float4*)(ap_);      B##a1 = *(const float4*)(ap_ + 4); \
    B##a2 = *(const float4*)(ap_ + 8);  B##a3 = *(const float4*)(ap_ + 12); \
    B##bt = myslot[(T)*128]; \
} while (0)

#define FWD_STEP(T, B, TL) do { \
    float p0_ = B##bt, p1_ = 0.f, p2_ = 0.f, p3_ = 0.f; \
    p0_ += B##a0.x*GSHFL(s,0)  + B##a0.y*GSHFL(s,1); \
    p1_ += B##a0.z*GSHFL(s,2)  + B##a0.w*GSHFL(s,3); \
    p2_ += B##a1.x*GSHFL(s,4)  + B##a1.y*GSHFL(s,5); \
    p3_ += B##a1.z*GSHFL(s,6)  + B##a1.w*GSHFL(s,7); \
    p0_ += B##a2.x*GSHFL(s,8)  + B##a2.y*GSHFL(s,9); \
    p1_ += B##a2.z*GSHFL(s,10) + B##a2.w*GSHFL(s,11); \
    p2_ += B##a3.x*GSHFL(s,12) + B##a3.y*GSHFL(s,13); \
    p3_ += B##a3.z*GSHFL(s,14) + B##a3.w*GSHFL(s,15); \
    const float sn_ = (p0_ + p1_) + (p2_ + p3_); \
    myslot[(T)*128] = sn_; \
    s = sn_; \
    if ((TL) < TS) FWD_LOAD(B, TL); \
} while (0)

#define BWD_LOAD(B, T) do { \
    const float* gp_ = Gw + (T)*(NS*NS) + lane*NS; \
    B##g0 = *(const float4*)(gp_);      B##g1 = *(const float4*)(gp_ + 4); \
    B##g2 = *(const float4*)(gp_ + 8);  B##g3 = *(const float4*)(gp_ + 12); \
    B##u  = *(const float4*)(up + ((T)+1)*CS); \
    B##sf = myslot[(T)*128]; \
} while (0)

#define BWD_STEP(T, B, TL) do { \
    float p0_ = Bci[0]*B##u.x + Bci[1]*B##u.y; \
    float p1_ = Bci[2]*B##u.z + Bci[3]*B##u.w; \
    float p2_ = 0.f, p3_ = 0.f; \
    _Pragma("unroll") \
    for (int k = 0; k < NS; k += 4) { \
        p0_ += Fi[k  ] * GSHFL(B##sf, k); \
        p1_ += Fi[k+1] * GSHFL(B##sf, k+1); \
        p2_ += Fi[k+2] * GSHFL(B##sf, k+2); \
        p3_ += Fi[k+3] * GSHFL(B##sf, k+3); \
    } \
    const float diff_ = ss - ((p0_ + p1_) + (p2_ + p3_)); \
    float a0_ = B##g0.x*GSHFL(diff_,0)  + B##g0.y*GSHFL(diff_,1); \
    a0_      += B##g0.z*GSHFL(diff_,2)  + B##g0.w*GSHFL(diff_,3); \
    float a1_ = B##g1.x*GSHFL(diff_,4)  + B##g1.y*GSHFL(diff_,5); \
    a1_      += B##g1.z*GSHFL(diff_,6)  + B##g1.w*GSHFL(diff_,7); \
    float a2_ = B##g2.x*GSHFL(diff_,8)  + B##g2.y*GSHFL(diff_,9); \
    a2_      += B##g2.z*GSHFL(diff_,10) + B##g2.w*GSHFL(diff_,11); \
    float a3_ = B##g3.x*GSHFL(diff_,12) + B##g3.y*GSHFL(diff_,13); \
    a3_      += B##g3.z*GSHFL(diff_,14) + B##g3.w*GSHFL(diff_,15); \
    const float sn_ = B##sf + ((a0_ + a1_) + (a2_ + a3_)); \
    ob[(T)*NS + lane] = sn_; \
    ss = sn_; \
    if ((TL) >= 0) BWD_LOAD(B, TL); \
} while (0)

__global__ __launch_bounds__(128, 1) void fb_kernel(
    const float* __restrict__ s0g, const float* __restrict__ Aw,
    const float* __restrict__ Gw, const float* __restrict__ ctrl,
    const float* __restrict__ Ag, const float* __restrict__ Bcg,
    float* __restrict__ outp)
{
    extern __shared__ float sfs[];     // [TS][8][NS] = 64KB
    const int tid  = threadIdx.x;
    const int lane = tid & 15;
    const int wb   = tid >> 4;
    const int b    = blockIdx.x * 8 + wb;
    float* ob = outp + (size_t)b * TS * NS;
    float* myslot = sfs + wb*NS + lane;

    // ---- bulk-load b_t (written by prep) into LDS, fully coalesced ----
    {
        const float4* src = (const float4*)(outp + (size_t)(blockIdx.x*8) * TS * NS);
        float4* dst = (float4*)sfs;
        for (int idx = tid; idx < 4096; idx += 128) {
            const int wb2 = idx >> 9;
            const int k   = idx & 511;
            const float4 v = src[idx];
            dst[(k >> 2)*32 + wb2*4 + (k & 3)] = v;
        }
    }
    __syncthreads();

    // ---------------- phase 1: forward filter (4-deep pipeline) ----------------
    {
        float s = s0g[b*NS + lane];
        float4 Aa0, Aa1, Aa2, Aa3; float Abt;
        float4 Ba0, Ba1, Ba2, Ba3; float Bbt;
        float4 Ca0, Ca1, Ca2, Ca3; float Cbt;
        float4 Da0, Da1, Da2, Da3; float Dbt;
        FWD_LOAD(A, 0); FWD_LOAD(B, 1); FWD_LOAD(C, 2); FWD_LOAD(D, 3);

        for (int tb = 0; tb <= TS-4; tb += 4) {
            FWD_STEP(tb,   A, tb+4);
            FWD_STEP(tb+1, B, tb+5);
            FWD_STEP(tb+2, C, tb+6);
            FWD_STEP(tb+3, D, tb+7);
        }
    }

    // ---------------- phase 2: backward smoother (4-deep pipeline) ----------------
    {
        float Fi[NS], Bci[CS];
#pragma unroll
        for (int k = 0; k < NS; ++k) Fi[k] = ((lane == k) ? 1.f : 0.f) + DTC * Ag[lane*NS + k];
#pragma unroll
        for (int k = 0; k < CS; ++k) Bci[k] = DTC * Bcg[lane*CS + k];
        const float* up = ctrl + (size_t)b * TS * CS;

        float ss = myslot[(TS-1)*128];
        ob[(TS-1)*NS + lane] = ss;             // s_s[T-1] = s_f[T-1]

        float4 Ag0, Ag1, Ag2, Ag3, Au; float Asf;
        float4 Bg0, Bg1, Bg2, Bg3, Bu; float Bsf;
        float4 Cg0, Cg1, Cg2, Cg3, Cu; float Csf;
        float4 Dg0, Dg1, Dg2, Dg3, Du; float Dsf;
        BWD_LOAD(A, TS-2); BWD_LOAD(B, TS-3); BWD_LOAD(C, TS-4); BWD_LOAD(D, TS-5);

        for (int tb = TS-2; tb >= 6; tb -= 4) {
            BWD_STEP(tb,   A, tb-4);
            BWD_STEP(tb-1, B, tb-5);
            BWD_STEP(tb-2, C, tb-6);
            BWD_STEP(tb-3, D, tb-7);
        }
        BWD_STEP(2, A, -1);
        BWD_STEP(1, B, -1);
        BWD_STEP(0, C, -1);
    }
}

extern "C" void kernel_launch(void* const* d_in, const int* in_sizes, int n_in,
                              void* d_out, int out_size, void* d_ws, size_t ws_size,
                              hipStream_t stream)
{
    (void)out_size; (void)ws_size;

    // Self-resolving input mapping from element counts (the round-4 fix):
    const float *s0 = nullptr, *P0 = nullptr, *ctrl = nullptr, *obs = nullptr;
    const float *A = nullptr, *Bc = nullptr, *H = nullptr, *Q = nullptr, *R = nullptr;
    for (int idx = 0; idx < n_in; ++idx) {
        const float* p = (const float*)d_in[idx];
        switch (in_sizes[idx]) {
            case NB*NS:        s0   = p; break;           // 32768
            case NB*NS*NS:     P0   = p; break;           // 524288
            case NB*TS*CS:     ctrl = p; break;           // 1048576
            case NB*TS*MS:     obs  = p; break;           // 2097152
            case MS*NS:        H    = p; break;           // 128
            case NS*NS:        if (!A)  A  = p; else Q = p; break;   // 256
            case MS*MS:        if (!Bc) Bc = p; else R = p; break;   // 64
            default: break;
        }
    }

    float* ws  = (float*)d_ws;
    float* Kw  = ws + K_OFF;
    float* Gw  = ws + G_OFF;
    float* Ppw = ws + PP_OFF;
    float* Pfw = ws + PF_OFF;
    float* Aw  = ws + A_OFF;
    float* Mw  = ws + M_OFF;
    float* out = (float*)d_out;

    hipLaunchKernelGGL(cov_kernel, dim3(1), dim3(256), 0, stream,
                       A, H, Q, R, P0, Bc, Kw, Ppw, Pfw, Aw, Mw);
    hipLaunchKernelGGL(gprep_kernel, dim3((TS-1) + NB*TS*NS/256), dim3(256), 0, stream,
                       A, Ppw, Pfw, Gw, ctrl, obs, Kw, Mw, out);
    hipLaunchKernelGGL(fb_kernel, dim3(NB/8), dim3(128), TS*8*NS*sizeof(float), stream,
                       s0, Aw, Gw, ctrl, A, Bc, out);
}